// Round 7
// baseline (1091.408 us; speedup 1.0000x reference)
//
#include <hip/hip_runtime.h>
#include <math.h>

#define NN 100000
#define DF 512
#define HID 16
#define NBUCK 392            // ceil(NN/256) buckets of 256 dst values (+1 spare)
#define EPB 4096             // edges per block in bucketA (256 thr x 16)
#define APAD 17              // LDS accumulator row stride (bank-spread padding)

// Flag: 1 if edge_index is int64-laid-out, 0 if int32.
__device__ int g_idx64;

__global__ void detect_idx_kernel(const long long* __restrict__ idx) {
    int lane = threadIdx.x;  // 64 threads
    int ok = 1;
    for (int i = lane; i < 128; i += 64) {
        long long v = idx[i];
        if (v < 0 || v >= NN) ok = 0;
    }
    unsigned long long m = __ballot(ok);
    if (lane == 0) g_idx64 = (m == ~0ULL);
}

// ---------------- GEMM1: h1 = x @ W1 -------------------------------------
// One thread per node; W1 via wave-uniform scalar loads; x streamed float4.
__global__ __launch_bounds__(64) void gemm1_kernel(
    const float* __restrict__ x, const float* __restrict__ W1,
    float* __restrict__ h1, int nN)
{
    int node = blockIdx.x * 64 + threadIdx.x;
    if (node >= nN) return;
    const float4* xr = (const float4*)(x + (size_t)node * DF);

    float acc[16];
#pragma unroll
    for (int c = 0; c < 16; ++c) acc[c] = 0.f;

#pragma unroll 4
    for (int kq = 0; kq < DF / 4; ++kq) {
        float4 xv = xr[kq];
        const float* wrow = W1 + kq * 4 * HID;  // wave-uniform address
        float xs[4] = {xv.x, xv.y, xv.z, xv.w};
#pragma unroll
        for (int j = 0; j < 4; ++j) {
            float s = xs[j];
#pragma unroll
            for (int c = 0; c < 16; ++c)
                acc[c] = fmaf(s, wrow[j * 16 + c], acc[c]);
        }
    }

    float4* o = (float4*)(h1 + (size_t)node * HID);
#pragma unroll
    for (int g = 0; g < 4; ++g)
        o[g] = make_float4(acc[g * 4 + 0], acc[g * 4 + 1],
                           acc[g * 4 + 2], acc[g * 4 + 3]);
}

// ---------------- Bucket-level histogram (LDS-first) -----------------------
__global__ __launch_bounds__(256) void bucket_hist_kernel(
    const void* __restrict__ eidx, int* __restrict__ bcnt, int nE)
{
    __shared__ int h[NBUCK];
    for (int i = threadIdx.x; i < NBUCK; i += 256) h[i] = 0;
    __syncthreads();
    const int i64 = g_idx64;
    int stride = gridDim.x * 256;
    for (int e = blockIdx.x * 256 + threadIdx.x; e < nE; e += stride) {
        int d;
        if (i64) d = (int)((const long long*)eidx)[nE + e];
        else     d = ((const int*)eidx)[nE + e];
        if ((unsigned)d < (unsigned)NN) atomicAdd(&h[d >> 8], 1);
    }
    __syncthreads();
    for (int i = threadIdx.x; i < NBUCK; i += 256)
        if (h[i]) atomicAdd(&bcnt[i], h[i]);
}

// ---------------- Scan of 392 bucket counts -> bbase / cursor --------------
__global__ __launch_bounds__(512) void bucket_scan_kernel(
    const int* __restrict__ bcnt, int* __restrict__ bbase,
    int* __restrict__ cursor)
{
    __shared__ int s[512];
    int t = threadIdx.x;
    int v = (t < NBUCK) ? bcnt[t] : 0;
    s[t] = v;
    __syncthreads();
    for (int off = 1; off < 512; off <<= 1) {
        int u = (t >= off) ? s[t - off] : 0;
        __syncthreads();
        s[t] += u;
        __syncthreads();
    }
    int excl = s[t] - v;   // exclusive prefix
    if (t < NBUCK) { bbase[t] = excl; cursor[t] = excl; }
    if (t == NBUCK) bbase[t] = excl;   // total
}

// ---------------- Pass A: coarse bucket sort -------------------------------
__global__ __launch_bounds__(256) void bucketA_kernel(
    const void* __restrict__ eidx, const float* __restrict__ ew,
    int* __restrict__ cursor, int2* __restrict__ packed, int nE)
{
    __shared__ int cnt[NBUCK];
    __shared__ int base[NBUCK];
    int t = threadIdx.x;
    for (int i = t; i < NBUCK; i += 256) cnt[i] = 0;
    __syncthreads();

    const int e0 = blockIdx.x * EPB;
    const int i64 = g_idx64;
    int lo[16]; float wv[16]; int bk[16];
#pragma unroll
    for (int i = 0; i < 16; ++i) {
        int e = e0 + t + i * 256;
        bk[i] = -1;
        if (e < nE) {
            int s, d;
            if (i64) {
                const long long* p = (const long long*)eidx;
                s = (int)p[e]; d = (int)p[nE + e];
            } else {
                const int* p = (const int*)eidx;
                s = p[e]; d = p[nE + e];
            }
            if ((unsigned)d < (unsigned)NN) {
                float w = ew[e];
                if ((unsigned)s >= (unsigned)NN) { s = 0; w = 0.f; }
                bk[i] = d >> 8;
                lo[i] = s | ((d & 255) << 20);
                wv[i] = w;
                atomicAdd(&cnt[bk[i]], 1);
            }
        }
    }
    __syncthreads();
    for (int i = t; i < NBUCK; i += 256)
        base[i] = (cnt[i] > 0) ? atomicAdd(&cursor[i], cnt[i]) : 0;
    __syncthreads();
    for (int i = t; i < NBUCK; i += 256) cnt[i] = 0;
    __syncthreads();
#pragma unroll
    for (int i = 0; i < 16; ++i) {
        if (bk[i] >= 0) {
            int r = atomicAdd(&cnt[bk[i]], 1);
            packed[base[bk[i]] + r] = make_int2(lo[i], __float_as_int(wv[i]));
        }
    }
}

// ---------------- Per-bucket LDS accumulation (shared device fn) -----------
// acc: 2 copies of 256 nodes x APAD floats. 4 lanes per edge; ds_add_f32.
__device__ __forceinline__ void bucket_accumulate(
    float* acc, const int2* __restrict__ packed,
    const float* __restrict__ h, int beg, int end, int t)
{
    int cp = (t >> 7) * 256 * APAD;   // waves 0,1 -> copy0; 2,3 -> copy1
    int c4 = t & 3;
    const float4* h4 = (const float4*)h;
    for (int p0 = beg; p0 < end; p0 += 256) {   // 256 edges per outer iter
        int2 e[4]; float4 v[4]; int idx[4]; bool ok[4];
#pragma unroll
        for (int i = 0; i < 4; ++i) {
            int p = p0 + i * 64 + (t >> 2);
            ok[i] = p < end;
            e[i] = ok[i] ? packed[p] : make_int2(0, __float_as_int(0.f));
        }
#pragma unroll
        for (int i = 0; i < 4; ++i) {
            int src = e[i].x & 0xFFFFF;
            v[i] = ok[i] ? h4[(size_t)src * 4 + c4]
                         : make_float4(0.f, 0.f, 0.f, 0.f);
            idx[i] = cp + ((e[i].x >> 20) & 255) * APAD + c4 * 4;
        }
#pragma unroll
        for (int i = 0; i < 4; ++i) {
            if (ok[i]) {
                float w = __int_as_float(e[i].y);
                atomicAdd(&acc[idx[i] + 0], w * v[i].x);
                atomicAdd(&acc[idx[i] + 1], w * v[i].y);
                atomicAdd(&acc[idx[i] + 2], w * v[i].z);
                atomicAdd(&acc[idx[i] + 3], w * v[i].w);
            }
        }
    }
}

// ---------------- Layer 1: agg1 + relu(+b1) @ W2 -> h2 ---------------------
__global__ __launch_bounds__(256) void agg1_kernel(
    const int2* __restrict__ packed, const int* __restrict__ bbase,
    const float* __restrict__ h1, const float* __restrict__ b1,
    const float* __restrict__ W2, float* __restrict__ h2, int nN)
{
    __shared__ float acc[2 * 256 * APAD];
    int t = threadIdx.x;
    int b = blockIdx.x;
    for (int i = t; i < 2 * 256 * APAD; i += 256) acc[i] = 0.f;
    __syncthreads();
    bucket_accumulate(acc, packed, h1, bbase[b], bbase[b + 1], t);
    __syncthreads();

    int node = b * 256 + t;
    if (node >= nN) return;
    float v[16];
#pragma unroll
    for (int c = 0; c < 16; ++c)
        v[c] = fmaxf(acc[t * APAD + c] + acc[256 * APAD + t * APAD + c] + b1[c], 0.f);
    float o[16];
#pragma unroll
    for (int c = 0; c < 16; ++c) o[c] = 0.f;
#pragma unroll
    for (int k = 0; k < 16; ++k) {
        float s = v[k];
#pragma unroll
        for (int c = 0; c < 16; ++c)
            o[c] = fmaf(s, W2[k * 16 + c], o[c]);   // wave-uniform scalar loads
    }
    float4* op = (float4*)(h2 + (size_t)node * 16);
#pragma unroll
    for (int g = 0; g < 4; ++g)
        op[g] = make_float4(o[g * 4 + 0], o[g * 4 + 1], o[g * 4 + 2], o[g * 4 + 3]);
}

// ---------------- Layer 2: agg2 + b2 -> log_softmax -> out -----------------
__global__ __launch_bounds__(256) void agg2_kernel(
    const int2* __restrict__ packed, const int* __restrict__ bbase,
    const float* __restrict__ h2, const float* __restrict__ b2,
    float* __restrict__ out, int nN)
{
    __shared__ float acc[2 * 256 * APAD];
    int t = threadIdx.x;
    int b = blockIdx.x;
    for (int i = t; i < 2 * 256 * APAD; i += 256) acc[i] = 0.f;
    __syncthreads();
    bucket_accumulate(acc, packed, h2, bbase[b], bbase[b + 1], t);
    __syncthreads();

    int node = b * 256 + t;
    if (node >= nN) return;
    float v[16];
#pragma unroll
    for (int c = 0; c < 16; ++c)
        v[c] = acc[t * APAD + c] + acc[256 * APAD + t * APAD + c] + b2[c];
    float m = v[0];
#pragma unroll
    for (int c = 1; c < 16; ++c) m = fmaxf(m, v[c]);
    float s = 0.f;
#pragma unroll
    for (int c = 0; c < 16; ++c) s += expf(v[c] - m);
    float l = m + logf(s);
    float4* op = (float4*)(out + (size_t)node * 16);
#pragma unroll
    for (int g = 0; g < 4; ++g)
        op[g] = make_float4(v[g * 4 + 0] - l, v[g * 4 + 1] - l,
                            v[g * 4 + 2] - l, v[g * 4 + 3] - l);
}

extern "C" void kernel_launch(void* const* d_in, const int* in_sizes, int n_in,
                              void* d_out, int out_size, void* d_ws, size_t ws_size,
                              hipStream_t stream)
{
    const float* x  = (const float*)d_in[0];
    const void*  ei = d_in[1];
    const float* ew = (const float*)d_in[2];
    const float* W1 = (const float*)d_in[3];
    const float* b1 = (const float*)d_in[4];
    const float* W2 = (const float*)d_in[5];
    const float* b2 = (const float*)d_in[6];
    float* out = (float*)d_out;

    const int N = NN;
    const int E = in_sizes[2];

    const size_t featB = (size_t)N * HID * sizeof(float);           // 6.4 MB
    const size_t bkB   = (((size_t)(NBUCK + 1) * 4) + 255) & ~255ULL;
    const size_t seB   = ((size_t)E * 8 + 255) & ~255ULL;           // 25.6 MB

    char* w = (char*)d_ws;
    float* buf0 = (float*)w;      w += (featB + 255) & ~255ULL;   // h1
    float* buf1 = (float*)w;      w += (featB + 255) & ~255ULL;   // h2
    int*   bcnt = (int*)w;        w += bkB;
    int*   bbase = (int*)w;       w += bkB;
    int*   cursor = (int*)w;      w += bkB;
    int2*  packed = (int2*)w;     w += seB;

    detect_idx_kernel<<<1, 64, 0, stream>>>((const long long*)ei);
    gemm1_kernel<<<(N + 63) / 64, 64, 0, stream>>>(x, W1, buf0, N);

    // Coarse bucket sort of edges by dst>>8.
    hipMemsetAsync(bcnt, 0, (size_t)NBUCK * 4, stream);
    bucket_hist_kernel<<<256, 256, 0, stream>>>(ei, bcnt, E);
    bucket_scan_kernel<<<1, 512, 0, stream>>>(bcnt, bbase, cursor);
    bucketA_kernel<<<(E + EPB - 1) / EPB, 256, 0, stream>>>(ei, ew, cursor, packed, E);

    // Per-bucket LDS aggregation with fused epilogues.
    agg1_kernel<<<NBUCK, 256, 0, stream>>>(packed, bbase, buf0, b1, W2, buf1, N);
    agg2_kernel<<<NBUCK, 256, 0, stream>>>(packed, bbase, buf1, b2, out, N);
}

// Round 8
// 1022.020 us; speedup vs baseline: 1.0679x; 1.0679x over previous
//
#include <hip/hip_runtime.h>
#include <math.h>

#define NN 100000
#define DF 512
#define HID 16
#define NBUCK 392            // ceil(NN/256) buckets of 256 dst values (+1 spare)
#define EPB 4096             // edges per block in bucketA (256 thr x 16)
#define APAD 17              // LDS accumulator row stride (bank-spread padding)
#define SPLIT 4              // slice-blocks per bucket in agg kernels

// Flag: 1 if edge_index is int64-laid-out, 0 if int32.
__device__ int g_idx64;

__global__ void detect_idx_kernel(const long long* __restrict__ idx) {
    int lane = threadIdx.x;  // 64 threads
    int ok = 1;
    for (int i = lane; i < 128; i += 64) {
        long long v = idx[i];
        if (v < 0 || v >= NN) ok = 0;
    }
    unsigned long long m = __ballot(ok);
    if (lane == 0) g_idx64 = (m == ~0ULL);
}

// ---------------- GEMM1: h1 = x @ W1 -------------------------------------
// One thread per node; W1 via wave-uniform scalar loads; x streamed float4.
__global__ __launch_bounds__(64) void gemm1_kernel(
    const float* __restrict__ x, const float* __restrict__ W1,
    float* __restrict__ h1, int nN)
{
    int node = blockIdx.x * 64 + threadIdx.x;
    if (node >= nN) return;
    const float4* xr = (const float4*)(x + (size_t)node * DF);

    float acc[16];
#pragma unroll
    for (int c = 0; c < 16; ++c) acc[c] = 0.f;

#pragma unroll 4
    for (int kq = 0; kq < DF / 4; ++kq) {
        float4 xv = xr[kq];
        const float* wrow = W1 + kq * 4 * HID;  // wave-uniform address
        float xs[4] = {xv.x, xv.y, xv.z, xv.w};
#pragma unroll
        for (int j = 0; j < 4; ++j) {
            float s = xs[j];
#pragma unroll
            for (int c = 0; c < 16; ++c)
                acc[c] = fmaf(s, wrow[j * 16 + c], acc[c]);
        }
    }

    float4* o = (float4*)(h1 + (size_t)node * HID);
#pragma unroll
    for (int g = 0; g < 4; ++g)
        o[g] = make_float4(acc[g * 4 + 0], acc[g * 4 + 1],
                           acc[g * 4 + 2], acc[g * 4 + 3]);
}

// ---------------- Bucket-level histogram (LDS-first) -----------------------
__global__ __launch_bounds__(256) void bucket_hist_kernel(
    const void* __restrict__ eidx, int* __restrict__ bcnt, int nE)
{
    __shared__ int h[NBUCK];
    for (int i = threadIdx.x; i < NBUCK; i += 256) h[i] = 0;
    __syncthreads();
    const int i64 = g_idx64;
    int stride = gridDim.x * 256;
    for (int e = blockIdx.x * 256 + threadIdx.x; e < nE; e += stride) {
        int d;
        if (i64) d = (int)((const long long*)eidx)[nE + e];
        else     d = ((const int*)eidx)[nE + e];
        if ((unsigned)d < (unsigned)NN) atomicAdd(&h[d >> 8], 1);
    }
    __syncthreads();
    for (int i = threadIdx.x; i < NBUCK; i += 256)
        if (h[i]) atomicAdd(&bcnt[i], h[i]);
}

// ---------------- Scan of 392 bucket counts -> bbase / cursor --------------
__global__ __launch_bounds__(512) void bucket_scan_kernel(
    const int* __restrict__ bcnt, int* __restrict__ bbase,
    int* __restrict__ cursor)
{
    __shared__ int s[512];
    int t = threadIdx.x;
    int v = (t < NBUCK) ? bcnt[t] : 0;
    s[t] = v;
    __syncthreads();
    for (int off = 1; off < 512; off <<= 1) {
        int u = (t >= off) ? s[t - off] : 0;
        __syncthreads();
        s[t] += u;
        __syncthreads();
    }
    int excl = s[t] - v;   // exclusive prefix
    if (t < NBUCK) { bbase[t] = excl; cursor[t] = excl; }
    if (t == NBUCK) bbase[t] = excl;   // total
}

// ---------------- Pass A: coarse bucket sort -------------------------------
__global__ __launch_bounds__(256) void bucketA_kernel(
    const void* __restrict__ eidx, const float* __restrict__ ew,
    int* __restrict__ cursor, int2* __restrict__ packed, int nE)
{
    __shared__ int cnt[NBUCK];
    __shared__ int base[NBUCK];
    int t = threadIdx.x;
    for (int i = t; i < NBUCK; i += 256) cnt[i] = 0;
    __syncthreads();

    const int e0 = blockIdx.x * EPB;
    const int i64 = g_idx64;
    int lo[16]; float wv[16]; int bk[16];
#pragma unroll
    for (int i = 0; i < 16; ++i) {
        int e = e0 + t + i * 256;
        bk[i] = -1;
        if (e < nE) {
            int s, d;
            if (i64) {
                const long long* p = (const long long*)eidx;
                s = (int)p[e]; d = (int)p[nE + e];
            } else {
                const int* p = (const int*)eidx;
                s = p[e]; d = p[nE + e];
            }
            if ((unsigned)d < (unsigned)NN) {
                float w = ew[e];
                if ((unsigned)s >= (unsigned)NN) { s = 0; w = 0.f; }
                bk[i] = d >> 8;
                lo[i] = s | ((d & 255) << 20);
                wv[i] = w;
                atomicAdd(&cnt[bk[i]], 1);
            }
        }
    }
    __syncthreads();
    for (int i = t; i < NBUCK; i += 256)
        base[i] = (cnt[i] > 0) ? atomicAdd(&cursor[i], cnt[i]) : 0;
    __syncthreads();
    for (int i = t; i < NBUCK; i += 256) cnt[i] = 0;
    __syncthreads();
#pragma unroll
    for (int i = 0; i < 16; ++i) {
        if (bk[i] >= 0) {
            int r = atomicAdd(&cnt[bk[i]], 1);
            packed[base[bk[i]] + r] = make_int2(lo[i], __float_as_int(wv[i]));
        }
    }
}

// ---------------- Agg slice kernel: LDS partial per (bucket, slice) --------
// Grid = NBUCK*SPLIT. Block (b,s) accumulates its quarter of bucket b's
// packed edges into a single-copy 256xAPAD LDS accumulator, then writes a
// coalesced 256x16 partial (no atomics).
__global__ __launch_bounds__(256) void agg_slice_kernel(
    const int2* __restrict__ packed, const int* __restrict__ bbase,
    const float* __restrict__ h, float* __restrict__ partial)
{
    __shared__ float acc[256 * APAD];
    int t = threadIdx.x;
    int b = blockIdx.x / SPLIT;
    int s = blockIdx.x % SPLIT;
    for (int i = t; i < 256 * APAD; i += 256) acc[i] = 0.f;
    __syncthreads();

    int beg = bbase[b], end = bbase[b + 1];
    int len = end - beg;
    int chunk = (len + SPLIT - 1) / SPLIT;
    int sb = beg + s * chunk;
    int sE = sb + chunk; if (sE > end) sE = end;

    int c4 = t & 3;
    const float4* h4 = (const float4*)h;
    for (int p0 = sb; p0 < sE; p0 += 256) {   // 256 edges per outer iter
        int2 e[4]; float4 v[4]; int idx[4]; bool ok[4];
#pragma unroll
        for (int i = 0; i < 4; ++i) {
            int p = p0 + i * 64 + (t >> 2);
            ok[i] = p < sE;
            e[i] = ok[i] ? packed[p] : make_int2(0, __float_as_int(0.f));
        }
#pragma unroll
        for (int i = 0; i < 4; ++i) {
            int src = e[i].x & 0xFFFFF;
            v[i] = ok[i] ? h4[(size_t)src * 4 + c4]
                         : make_float4(0.f, 0.f, 0.f, 0.f);
            idx[i] = ((e[i].x >> 20) & 255) * APAD + c4 * 4;
        }
#pragma unroll
        for (int i = 0; i < 4; ++i) {
            if (ok[i]) {
                float w = __int_as_float(e[i].y);
                atomicAdd(&acc[idx[i] + 0], w * v[i].x);
                atomicAdd(&acc[idx[i] + 1], w * v[i].y);
                atomicAdd(&acc[idx[i] + 2], w * v[i].z);
                atomicAdd(&acc[idx[i] + 3], w * v[i].w);
            }
        }
    }
    __syncthreads();

    // write partial: thread t owns node-local t (4 float4s, coalesced)
    float4* op = (float4*)(partial + (size_t)blockIdx.x * 256 * 16 + t * 16);
#pragma unroll
    for (int g = 0; g < 4; ++g)
        op[g] = make_float4(acc[t * APAD + g * 4 + 0], acc[t * APAD + g * 4 + 1],
                            acc[t * APAD + g * 4 + 2], acc[t * APAD + g * 4 + 3]);
}

// ---------------- Epilogue 1: sum partials + relu(+b1) @ W2 -> h2 ----------
__global__ __launch_bounds__(256) void epi1_kernel(
    const float* __restrict__ partial, const float* __restrict__ b1,
    const float* __restrict__ W2, float* __restrict__ h2, int nN)
{
    int node = blockIdx.x * 256 + threadIdx.x;
    if (node >= nN) return;
    int b = node >> 8, l = node & 255;
    const float4* p0 = (const float4*)(partial + ((size_t)(b * SPLIT) * 256 + l) * 16);
    float v[16];
#pragma unroll
    for (int g = 0; g < 4; ++g) {
        float4 a = p0[g];
        v[g * 4 + 0] = a.x; v[g * 4 + 1] = a.y; v[g * 4 + 2] = a.z; v[g * 4 + 3] = a.w;
    }
#pragma unroll
    for (int s = 1; s < SPLIT; ++s) {
        const float4* ps = (const float4*)(partial + ((size_t)(b * SPLIT + s) * 256 + l) * 16);
#pragma unroll
        for (int g = 0; g < 4; ++g) {
            float4 a = ps[g];
            v[g * 4 + 0] += a.x; v[g * 4 + 1] += a.y; v[g * 4 + 2] += a.z; v[g * 4 + 3] += a.w;
        }
    }
#pragma unroll
    for (int c = 0; c < 16; ++c) v[c] = fmaxf(v[c] + b1[c], 0.f);
    float o[16];
#pragma unroll
    for (int c = 0; c < 16; ++c) o[c] = 0.f;
#pragma unroll
    for (int k = 0; k < 16; ++k) {
        float s = v[k];
#pragma unroll
        for (int c = 0; c < 16; ++c)
            o[c] = fmaf(s, W2[k * 16 + c], o[c]);   // wave-uniform scalar loads
    }
    float4* op = (float4*)(h2 + (size_t)node * 16);
#pragma unroll
    for (int g = 0; g < 4; ++g)
        op[g] = make_float4(o[g * 4 + 0], o[g * 4 + 1], o[g * 4 + 2], o[g * 4 + 3]);
}

// ---------------- Epilogue 2: sum partials + b2 -> log_softmax -> out ------
__global__ __launch_bounds__(256) void epi2_kernel(
    const float* __restrict__ partial, const float* __restrict__ b2,
    float* __restrict__ out, int nN)
{
    int node = blockIdx.x * 256 + threadIdx.x;
    if (node >= nN) return;
    int b = node >> 8, l = node & 255;
    float v[16];
    const float4* p0 = (const float4*)(partial + ((size_t)(b * SPLIT) * 256 + l) * 16);
#pragma unroll
    for (int g = 0; g < 4; ++g) {
        float4 a = p0[g];
        v[g * 4 + 0] = a.x; v[g * 4 + 1] = a.y; v[g * 4 + 2] = a.z; v[g * 4 + 3] = a.w;
    }
#pragma unroll
    for (int s = 1; s < SPLIT; ++s) {
        const float4* ps = (const float4*)(partial + ((size_t)(b * SPLIT + s) * 256 + l) * 16);
#pragma unroll
        for (int g = 0; g < 4; ++g) {
            float4 a = ps[g];
            v[g * 4 + 0] += a.x; v[g * 4 + 1] += a.y; v[g * 4 + 2] += a.z; v[g * 4 + 3] += a.w;
        }
    }
#pragma unroll
    for (int c = 0; c < 16; ++c) v[c] += b2[c];
    float m = v[0];
#pragma unroll
    for (int c = 1; c < 16; ++c) m = fmaxf(m, v[c]);
    float s = 0.f;
#pragma unroll
    for (int c = 0; c < 16; ++c) s += expf(v[c] - m);
    float l2 = m + logf(s);
    float4* op = (float4*)(out + (size_t)node * 16);
#pragma unroll
    for (int g = 0; g < 4; ++g)
        op[g] = make_float4(v[g * 4 + 0] - l2, v[g * 4 + 1] - l2,
                            v[g * 4 + 2] - l2, v[g * 4 + 3] - l2);
}

extern "C" void kernel_launch(void* const* d_in, const int* in_sizes, int n_in,
                              void* d_out, int out_size, void* d_ws, size_t ws_size,
                              hipStream_t stream)
{
    const float* x  = (const float*)d_in[0];
    const void*  ei = d_in[1];
    const float* ew = (const float*)d_in[2];
    const float* W1 = (const float*)d_in[3];
    const float* b1 = (const float*)d_in[4];
    const float* W2 = (const float*)d_in[5];
    const float* b2 = (const float*)d_in[6];
    float* out = (float*)d_out;

    const int N = NN;
    const int E = in_sizes[2];

    const size_t featB = (size_t)N * HID * sizeof(float);            // 6.4 MB
    const size_t bkB   = (((size_t)(NBUCK + 1) * 4) + 255) & ~255ULL;
    const size_t seB   = ((size_t)E * 8 + 255) & ~255ULL;            // 25.6 MB
    const size_t partB = (size_t)NBUCK * SPLIT * 256 * 16 * 4;       // 25.7 MB

    char* w = (char*)d_ws;
    float* buf0 = (float*)w;      w += (featB + 255) & ~255ULL;   // h1
    float* buf1 = (float*)w;      w += (featB + 255) & ~255ULL;   // h2
    int*   bcnt = (int*)w;        w += bkB;
    int*   bbase = (int*)w;       w += bkB;
    int*   cursor = (int*)w;      w += bkB;
    int2*  packed = (int2*)w;     w += seB;
    float* partial = (float*)w;   w += (partB + 255) & ~255ULL;

    detect_idx_kernel<<<1, 64, 0, stream>>>((const long long*)ei);
    gemm1_kernel<<<(N + 63) / 64, 64, 0, stream>>>(x, W1, buf0, N);

    // Coarse bucket sort of edges by dst>>8.
    hipMemsetAsync(bcnt, 0, (size_t)NBUCK * 4, stream);
    bucket_hist_kernel<<<256, 256, 0, stream>>>(ei, bcnt, E);
    bucket_scan_kernel<<<1, 512, 0, stream>>>(bcnt, bbase, cursor);
    bucketA_kernel<<<(E + EPB - 1) / EPB, 256, 0, stream>>>(ei, ew, cursor, packed, E);

    const int nb = (N + 255) / 256;
    // Layer 1: sliced LDS aggregation -> partials -> fused epilogue.
    agg_slice_kernel<<<NBUCK * SPLIT, 256, 0, stream>>>(packed, bbase, buf0, partial);
    epi1_kernel<<<nb, 256, 0, stream>>>(partial, b1, W2, buf1, N);
    // Layer 2.
    agg_slice_kernel<<<NBUCK * SPLIT, 256, 0, stream>>>(packed, bbase, buf1, partial);
    epi2_kernel<<<nb, 256, 0, stream>>>(partial, b2, out, N);
}